// Round 7
// baseline (1160.046 us; speedup 1.0000x reference)
//
#include <hip/hip_runtime.h>
#include <hip/hip_bf16.h>
#include <math.h>

#define DIMC 1024
#define NHEADC 16
#define DKC 64
#define HIDC 8192
#define TSEQ 2048
#define BATCH 2
#define NROWS (BATCH*TSEQ)   // 4096
#define EPSF 1e-5f

typedef __attribute__((ext_vector_type(8))) short short8;
typedef __attribute__((ext_vector_type(4))) float floatx4;

// ---------------- helpers ----------------
__device__ __forceinline__ unsigned pk2bf(float a, float b){
  float2 t; t.x = a; t.y = b;
  __hip_bfloat162 h = __float22bfloat162_rn(t);   // v_cvt_pk_bf16_f32 on gfx950
  union { __hip_bfloat162 h; unsigned u; } cv; cv.h = h;
  return cv.u;                                    // a in low 16, b in high 16
}
__device__ __forceinline__ ushort f2bf(float f){
  return (ushort)(pk2bf(f, f) & 0xFFFFu);
}
__device__ __forceinline__ floatx4 mfma16(short8 a, short8 b, floatx4 c){
  return __builtin_amdgcn_mfma_f32_16x16x32_bf16(a, b, c, 0, 0, 0);
}
__device__ __forceinline__ void gld_lds16(const void* g, void* l){
  __builtin_amdgcn_global_load_lds((const __attribute__((address_space(1))) unsigned*)g,
                                   (__attribute__((address_space(3))) unsigned*)l, 16, 0, 0);
}
__device__ __forceinline__ float wred_add(float v){
  #pragma unroll
  for (int o = 32; o > 0; o >>= 1) v += __shfl_xor(v, o, 64);
  return v;
}
__device__ __forceinline__ float wred_max(float v){
  #pragma unroll
  for (int o = 32; o > 0; o >>= 1) v = fmaxf(v, __shfl_xor(v, o, 64));
  return v;
}
__device__ __forceinline__ float wred_min(float v){
  #pragma unroll
  for (int o = 32; o > 0; o >>= 1) v = fminf(v, __shfl_xor(v, o, 64));
  return v;
}
__device__ __forceinline__ int wred_addi(int v){
  #pragma unroll
  for (int o = 32; o > 0; o >>= 1) v += __shfl_xor(v, o, 64);
  return v;
}
__device__ __forceinline__ float lo16f(unsigned u){ return __uint_as_float(u << 16); }
__device__ __forceinline__ float hi16f(unsigned u){ return __uint_as_float(u & 0xFFFF0000u); }
// monotone bf16-bits -> u16 key
__device__ __forceinline__ unsigned f2key(float f){
  const unsigned b = __float_as_uint(f) >> 16;
  return (b & 0x8000u) ? (0xFFFFu - b) : (b + 0x8000u);
}
// opaque register pin (r1 evidence: keeps values out of LDS-remat; safe here
// because the 512-thr/(512,4) config has a 128-reg budget - proven no-spill)
__device__ __forceinline__ void pin(float& x){ asm volatile("" : "+v"(x)); }

// ---------------- weight transpose + fp32->bf16 convert: W[K][N] -> WT[N][K] ----
__global__ __launch_bounds__(256)
void wconv_t(const float* __restrict__ W, ushort* __restrict__ WT, int K, int N)
{
  __shared__ float tile[32][33];
  const int t = threadIdx.x, tx = t & 31, ty = t >> 5;
  const int n0 = blockIdx.x * 32, k0 = blockIdx.y * 32;
  #pragma unroll
  for (int r = 0; r < 4; ++r)
    tile[ty + r*8][tx] = W[(size_t)(k0 + ty + r*8) * N + n0 + tx];
  __syncthreads();
  #pragma unroll
  for (int r = 0; r < 4; ++r)
    WT[(size_t)(n0 + ty + r*8) * K + k0 + tx] = f2bf(tile[tx][ty + r*8]);
}

// ---------------- V transpose: qkv V-part -> vT[bh][64][2048] ----------------
__global__ __launch_bounds__(256)
void vtrans(const ushort* __restrict__ qkv, ushort* __restrict__ vT)
{
  const int d = threadIdx.x & 63, tp = threadIdx.x >> 6;
  const int bh = blockIdx.y; const int h = bh & 15, b = bh >> 4;
  const int t0 = blockIdx.x * 32 + tp * 8;
  const ushort* src = qkv + ((size_t)(b*TSEQ) + t0) * (3*DIMC) + 2*DIMC + h*DKC + d;
  ushort tmp[8];
  #pragma unroll
  for (int k = 0; k < 8; ++k) tmp[k] = src[(size_t)k * (3*DIMC)];
  *(short8*)&vT[((size_t)bh*DKC + d)*TSEQ + t0] = *(const short8*)tmp;
}

// ---------------- LayerNorm fp32 in -> bf16 out ----------------
__global__ __launch_bounds__(256)
void ln_bf16(const float* __restrict__ x, const float* __restrict__ g,
             const float* __restrict__ b, ushort* __restrict__ y)
{
  __shared__ float red[8];
  const int row = blockIdx.x;
  const float* xr = x + (size_t)row * DIMC;
  const int c = threadIdx.x * 4;
  float4 v = *(const float4*)&xr[c];
  float s  = v.x + v.y + v.z + v.w;
  float ss = v.x*v.x + v.y*v.y + v.z*v.z + v.w*v.w;
  s = wred_add(s); ss = wred_add(ss);
  const int warp = threadIdx.x >> 6, lane = threadIdx.x & 63;
  if (lane == 0) { red[warp] = s; red[4+warp] = ss; }
  __syncthreads();
  s  = red[0] + red[1] + red[2] + red[3];
  ss = red[4] + red[5] + red[6] + red[7];
  const float mu  = s  * (1.f/DIMC);
  const float var = ss * (1.f/DIMC) - mu*mu;
  const float rr  = rsqrtf(var + EPSF);
  const float4 gv = *(const float4*)&g[c];
  const float4 bv = *(const float4*)&b[c];
  uint2 o;
  o.x = pk2bf((v.x-mu)*rr*gv.x + bv.x, (v.y-mu)*rr*gv.y + bv.y);
  o.y = pk2bf((v.z-mu)*rr*gv.z + bv.z, (v.w-mu)*rr*gv.w + bv.w);
  *(uint2*)&y[(size_t)row*DIMC + c] = o;
}

// ---------------- bf16 MFMA GEMM: C[M,N] = A[M,K] @ BT[N,K]^T (+ epilogue) ----
#define M_PLAIN 0      // out bf16
#define M_RES 1        // out fp32: C = res + alpha*acc
#define M_BIAS_GELU 2  // out bf16: C = gelu_exact(acc + bias)
#define M_BIAS_RES 3   // out fp32: C = res + alpha*(acc + bias)

template<int MODE>
__global__ __launch_bounds__(256)
void gemm_bf16(const ushort* __restrict__ A, const ushort* __restrict__ BT,
               void* __restrict__ Cout, const int M, const int N, const int K,
               const float* __restrict__ bias, const float* __restrict__ res,
               const float* __restrict__ alphap)
{
  __shared__ __align__(16) ushort Al[4][128][8];
  __shared__ __align__(16) ushort Bl[4][128][8];
  const int t = threadIdx.x;
  const int lane = t & 63, warp = t >> 6;
  const int quad = lane >> 4, l16 = lane & 15;
  const int m0 = (warp & 1) * 64, n0 = (warp >> 1) * 64;
  const size_t row0 = (size_t)blockIdx.y * 128;
  const size_t col0 = (size_t)blockIdx.x * 128;

  const int c0 = t, c1 = t + 256;
  const int ar0 = c0 & 127, as0 = c0 >> 7;
  const int ar1 = c1 & 127, as1 = c1 >> 7;
  const ushort* pa0 = A  + (row0 + ar0) * (size_t)K + as0 * 8;
  const ushort* pa1 = A  + (row0 + ar1) * (size_t)K + as1 * 8;
  const ushort* pb0 = BT + (col0 + ar0) * (size_t)K + as0 * 8;
  const ushort* pb1 = BT + (col0 + ar1) * (size_t)K + as1 * 8;
  ushort* la0 = &Al[as0][ar0][0];
  ushort* la1 = &Al[as1][ar1][0];
  ushort* lb0 = &Bl[as0][ar0][0];
  ushort* lb1 = &Bl[as1][ar1][0];

  floatx4 acc[4][4];
  const floatx4 zf = {0.f, 0.f, 0.f, 0.f};
  #pragma unroll
  for (int i = 0; i < 4; ++i)
    #pragma unroll
    for (int j = 0; j < 4; ++j) acc[i][j] = zf;

  for (int k0 = 0; k0 < K; k0 += 32) {
    gld_lds16(pa0 + k0, la0);
    gld_lds16(pa1 + k0, la1);
    gld_lds16(pb0 + k0, lb0);
    gld_lds16(pb1 + k0, lb1);
    __syncthreads();
    short8 af[4], bfr[4];
    #pragma unroll
    for (int i = 0; i < 4; ++i) {
      af[i]  = *(const short8*)&Al[quad][m0 + i*16 + l16][0];
      bfr[i] = *(const short8*)&Bl[quad][n0 + i*16 + l16][0];
    }
    #pragma unroll
    for (int mt = 0; mt < 4; ++mt)
      #pragma unroll
      for (int nt = 0; nt < 4; ++nt)
        acc[mt][nt] = mfma16(af[mt], bfr[nt], acc[mt][nt]);
    __syncthreads();
  }

  float alpha = 0.f;
  if (MODE == M_RES || MODE == M_BIAS_RES) alpha = alphap[0];
  #pragma unroll
  for (int nt = 0; nt < 4; ++nt) {
    const size_t col = col0 + n0 + nt*16 + l16;
    float bv = 0.f;
    if (MODE == M_BIAS_GELU || MODE == M_BIAS_RES) bv = bias[col];
    #pragma unroll
    for (int mt = 0; mt < 4; ++mt) {
      const size_t r0 = row0 + m0 + mt*16 + quad*4;
      #pragma unroll
      for (int reg = 0; reg < 4; ++reg) {
        float v = acc[mt][nt][reg];
        if (MODE == M_BIAS_GELU || MODE == M_BIAS_RES) v += bv;
        if (MODE == M_BIAS_GELU) v = 0.5f*v*(1.f + erff(v*0.70710678118654752f));
        if (MODE == M_RES || MODE == M_BIAS_RES) v = res[(r0+reg)*(size_t)N + col] + alpha*v;
        if (MODE == M_PLAIN || MODE == M_BIAS_GELU)
          ((ushort*)Cout)[(r0+reg)*(size_t)N + col] = f2bf(v);
        else
          ((float*)Cout)[(r0+reg)*(size_t)N + col] = v;
      }
    }
  }
}

// ---------------- fused MFMA attention ----------------
// v7: block = 512 thr (8 waves), strip = 8 q-rows. Rationale (r0-r6):
// at the 1024-thr/(1024,8) 64-reg cap the allocator ALWAYS lands at 32 arch
// VGPRs + ~95-114 MB scratch, regardless of phase-2 implementation; at cap
// 128 (r1) it never spills (40-64 regs) but a 16-wave block quantizes
// occupancy to 1 block/CU (48%). 8-wave blocks break that quantization:
// (512,4) gives the proven no-spill 128-reg budget, and a <=64-reg
// allocation lets the HW place 4 blocks/CU (32 waves, full occupancy).
// LDS = 8*2048*2 (S) + 4*272*4 (Ored) ~= 36.5 KB -> 4 blocks fit in 160 KB.
// Phase 1/3 MFMA tiles span 16 rows for 8 useful rows (2x MFMA waste; MFMA
// is ~4% util so this is noise). Phase 2 unchanged: 1 q-row per wave.
__device__ __forceinline__ int swzf(int q){ return ((q>>2) ^ q) & 7; }
__device__ __forceinline__ int sidx(int q, int j){
  return (q << 11) + ((((j >> 3) ^ swzf(q)) << 3) | (j & 7));
}

__global__ __launch_bounds__(512, 4)
void attn_mfma(const ushort* __restrict__ qkv, const ushort* __restrict__ vT,
               const float* __restrict__ alpha_head, ushort* __restrict__ att)
{
  __shared__ __align__(16) ushort S[8*2048];
  __shared__ float Ored[4][16*17];
  const int t = threadIdx.x;
  const int lane = t & 63, warp = t >> 6;      // warp in [0,8)
  const int quad = lane >> 4, l16 = lane & 15;
  const int blk = blockIdx.x;                  // 8192 = 32 bh * 256 q-chunks
  const int bh  = blk >> 8;
  const int q0  = (blk & 255) << 3;            // 8-row strip
  const int h = bh & (NHEADC-1), b = bh >> 4;
  const size_t rowbase = (size_t)b * TSEQ;
  const floatx4 zf = {0.f, 0.f, 0.f, 0.f};

  // --- phase 1: raw scores S[q][j] = Q.K^T for 8 rows (A rows duplicated) ---
  {
    const ushort* Qp = qkv + (rowbase + q0 + (l16 & 7)) * (size_t)(3*DIMC) + h*DKC + quad*8;
    const short8 aq0 = *(const short8*)Qp;
    const short8 aq1 = *(const short8*)(Qp + 32);
    const int j0w = warp * 256;
    #pragma unroll
    for (int jt = 0; jt < 16; ++jt) {
      const int j = j0w + jt*16;
      const ushort* Kp = qkv + (rowbase + j + l16) * (size_t)(3*DIMC) + DIMC + h*DKC + quad*8;
      const short8 kb0 = *(const short8*)Kp;
      const short8 kb1 = *(const short8*)(Kp + 32);
      floatx4 c = mfma16(aq0, kb0, zf);
      c = mfma16(aq1, kb1, c);
      if (quad < 2) {                          // out rows 0..7 only (8..15 dup)
        #pragma unroll
        for (int r = 0; r < 4; ++r)
          S[sidx(quad*4 + r, j + l16)] = f2bf(c[r]);
      }
    }
  }
  __syncthreads();

  // --- phase 2: per-row exact top-64 + softmax mix; 1 row per wave (8 rows) ---
  const float SC2 = 0.125f * 1.4426950408889634f;   // (1/sqrt(dk)) * log2(e)
  const float gate = 1.f / (1.f + __expf(-alpha_head[h]));
  {
    const int q = warp;
    const int sbase = q << 11;
    const int swq = swzf(q);
    // lane owns elements j = 2*lane + 128*p (p in [0,16)); unpack once, pin.
    float s[32];
    float lmx = -3.0e38f;
    #pragma unroll
    for (int p = 0; p < 16; ++p) {
      const int j = 2*lane + 128*p;
      const int g = (j >> 3) ^ swq;
      const unsigned u = *(const unsigned*)&S[sbase + (g << 3) + (j & 7)];
      s[2*p]   = lo16f(u);
      s[2*p+1] = hi16f(u);
      pin(s[2*p]); pin(s[2*p+1]);
      lmx = fmaxf(lmx, fmaxf(s[2*p], s[2*p+1]));
    }
    const float mx = wred_max(lmx);
    const float lb = wred_min(lmx);  // 64 lane-maxima => 64th-largest >= lb
    const float nc = -mx * SC2;

    // radix-select 64th largest in bf16-key space; compares in float domain.
    const unsigned kmx = f2key(mx), klb = f2key(lb);
    const unsigned diff = kmx ^ klb;
    unsigned prefix;
    int hb;
    if (diff == 0u) { prefix = kmx; hb = -1; }
    else {
      hb = 31 - __builtin_clz(diff);             // <=15 (16-bit keys)
      prefix = kmx & ~((2u << hb) - 1u);
    }
    hb = __builtin_amdgcn_readfirstlane(hb);
    for (int bit = hb; bit >= 0; --bit) {
      const unsigned cand = prefix | (1u << bit);
      const unsigned ub = (cand >= 0x8000u) ? (cand - 0x8000u) : (0xFFFFu - cand);
      const float candf = __uint_as_float(ub << 16);
      int c = 0;
      #pragma unroll
      for (int e = 0; e < 32; ++e) c += (s[e] >= candf) ? 1 : 0;
      c = wred_addi(c);
      prefix = (c >= 64) ? cand : prefix;
    }
    const unsigned ubf = (prefix >= 0x8000u) ? (prefix - 0x8000u) : (0xFFFFu - prefix);
    const float thf = __uint_as_float(ubf << 16);

    // classification: strict-greater, then ties by lowest j (jax top_k order)
    unsigned inmask = 0u;
    int cg = 0;
    #pragma unroll
    for (int e = 0; e < 32; ++e) {
      const bool gt = s[e] > thf;
      cg += gt ? 1 : 0;
      if (gt) inmask |= (1u << e);
    }
    const int c_gt = wred_addi(cg);
    const int need_eq = 64 - c_gt;   // >=1
    int eqb = 0;
    const unsigned long long below = (1ULL << lane) - 1ULL;
    #pragma unroll
    for (int p = 0; p < 16; ++p) {
      const bool e0 = (s[2*p]   == thf);
      const bool e1 = (s[2*p+1] == thf);
      const unsigned long long m0 = __ballot(e0);
      const unsigned long long m1 = __ballot(e1);
      if (m0 | m1) {
        const int r0 = eqb + __popcll(m0 & below) + __popcll(m1 & below);
        const int r1 = r0 + (e0 ? 1 : 0);
        if (e0 && r0 < need_eq) inmask |= (1u << (2*p));
        if (e1 && r1 < need_eq) inmask |= (1u << (2*p+1));
        eqb += __popcll(m0) + __popcll(m1);
      }
    }

    // denominators; cache exp in s[] (scores dead afterwards; pin exp results)
    float sum_all = 0.f, sum_sp = 0.f;
    #pragma unroll
    for (int e = 0; e < 32; ++e) {
      float ex = exp2f(fmaf(s[e], SC2, nc));
      pin(ex);
      s[e] = ex;
      sum_all += ex;
      sum_sp  += ((inmask >> e) & 1u) ? ex : 0.f;
    }
    sum_all = wred_add(sum_all);
    sum_sp  = wred_add(sum_sp);

    const float cd  = gate / sum_all;
    const float cdc = cd + (1.f - gate) / sum_sp;
    #pragma unroll
    for (int p = 0; p < 16; ++p) {
      const float w0 = s[2*p]   * (((inmask >> (2*p))   & 1u) ? cdc : cd);
      const float w1 = s[2*p+1] * (((inmask >> (2*p+1)) & 1u) ? cdc : cd);
      const int j = 2*lane + 128*p;
      const int g = (j >> 3) ^ swq;
      *(unsigned*)&S[sbase + (g << 3) + (j & 7)] = pk2bf(w0, w1);
    }
  }
  __syncthreads();

  // --- phase 3: O[8q x 64d] = W[8x2048] @ V[2048x64]; 4n x 2k wave grid ---
  const int ng = warp & 3, kq = warp >> 2;     // kq in [0,2)
  const int n0  = ng * 16;
  const int kt0 = kq * 32;
  floatx4 o = zf, o2 = zf;
  const ushort* Vb = vT + ((size_t)bh*DKC + n0 + l16) * TSEQ + quad*8;
  #pragma unroll 2
  for (int tt = 0; tt < 32; tt += 2) {
    const int kt = kt0 + tt;
    const short8 a0 = *(const short8*)&S[sidx(l16 & 7, kt*32 + quad*8)];
    const short8 vb0 = *(const short8*)(Vb + (size_t)kt*32);
    const short8 a1 = *(const short8*)&S[sidx(l16 & 7, (kt+1)*32 + quad*8)];
    const short8 vb1 = *(const short8*)(Vb + (size_t)(kt+1)*32);
    o  = mfma16(a0, vb0, o);
    o2 = mfma16(a1, vb1, o2);
  }
  o = o + o2;
  if (kq == 1) {
    #pragma unroll
    for (int r = 0; r < 4; ++r) Ored[ng][(quad*4+r)*17 + l16] = o[r];
  }
  __syncthreads();
  if (kq == 0 && quad < 2) {                   // rows 0..7 only
    #pragma unroll
    for (int r = 0; r < 4; ++r) {
      const int ri = (quad*4+r)*17 + l16;
      const float v = o[r] + Ored[ng][ri];
      att[(rowbase + q0 + quad*4 + r) * (size_t)DIMC + h*DKC + n0 + l16] = f2bf(v);
    }
  }
}

// ---------------- launch ----------------
extern "C" void kernel_launch(void* const* d_in, const int* in_sizes, int n_in,
                              void* d_out, int out_size, void* d_ws, size_t ws_size,
                              hipStream_t stream)
{
  const float* x          = (const float*)d_in[0];
  const float* ln1_g      = (const float*)d_in[1];
  const float* ln1_b      = (const float*)d_in[2];
  const float* w_qkv      = (const float*)d_in[3];
  const float* alpha_head = (const float*)d_in[4];
  const float* w_out      = (const float*)d_in[5];
  const float* ln2_g      = (const float*)d_in[6];
  const float* ln2_b      = (const float*)d_in[7];
  const float* w1         = (const float*)d_in[8];
  const float* b1         = (const float*)d_in[9];
  const float* w2         = (const float*)d_in[10];
  const float* b2         = (const float*)d_in[11];
  const float* alphap     = (const float*)d_in[12];
  float* out = (float*)d_out;

  char* ws = (char*)d_ws;
  ushort* wT_qkv = (ushort*)(ws);                         //  6 MB  [3072][1024]
  ushort* wT_out = (ushort*)(ws + 6291456);               //  2 MB  [1024][1024]
  ushort* wT_1   = (ushort*)(ws + 8388608);               // 16 MB  [8192][1024]
  ushort* wT_2   = (ushort*)(ws + 25165824);              // 16 MB  [1024][8192]
  ushort* xn     = (ushort*)(ws + 41943040);              //  8 MB  [4096][1024]
  ushort* qkv    = (ushort*)(ws + 50331648);              // 24 MB  [4096][3072]
  ushort* attb   = (ushort*)(ws + 75497472);              //  8 MB  [4096][1024]
  float*  x2     = (float*) (ws + 83886080);              // 16 MB  [4096][1024]
  ushort* hbuf   = (ushort*)(ws + 100663296);             // 64 MB  [4096][8192]
  ushort* vT     = (ushort*)(ws + 167772160);             //  8 MB  [32][64][2048]

  wconv_t<<<dim3(3072/32, 1024/32), 256, 0, stream>>>(w_qkv, wT_qkv, 1024, 3072);
  wconv_t<<<dim3(1024/32, 1024/32), 256, 0, stream>>>(w_out, wT_out, 1024, 1024);
  wconv_t<<<dim3(8192/32, 1024/32), 256, 0, stream>>>(w1,    wT_1,   1024, 8192);
  wconv_t<<<dim3(1024/32, 8192/32), 256, 0, stream>>>(w2,    wT_2,   8192, 1024);

  // 1) LN1 -> bf16
  ln_bf16<<<NROWS, 256, 0, stream>>>(x, ln1_g, ln1_b, xn);
  // 2) qkv = xn @ w_qkv  (bf16 out)
  gemm_bf16<M_PLAIN><<<dim3(3*DIMC/128, NROWS/128), 256, 0, stream>>>(
      xn, wT_qkv, qkv, NROWS, 3*DIMC, DIMC, nullptr, nullptr, nullptr);
  // 2b) V transpose
  vtrans<<<dim3(64, 32), 256, 0, stream>>>(qkv, vT);
  // 3) adaptive sparse attention (bf16 out); 32 bh * 256 8-row chunks
  attn_mfma<<<8192, 512, 0, stream>>>(qkv, vT, alpha_head, attb);
  // 4) x2 = x + alpha * (att @ w_out)  (fp32 out)
  gemm_bf16<M_RES><<<dim3(DIMC/128, NROWS/128), 256, 0, stream>>>(
      attb, wT_out, x2, NROWS, DIMC, DIMC, nullptr, x, alphap);
  // 5) LN2 -> bf16 (reuse xn)
  ln_bf16<<<NROWS, 256, 0, stream>>>(x2, ln2_g, ln2_b, xn);
  // 6) h = gelu(xn @ w1 + b1)  (bf16 out)
  gemm_bf16<M_BIAS_GELU><<<dim3(HIDC/128, NROWS/128), 256, 0, stream>>>(
      xn, wT_1, hbuf, NROWS, HIDC, DIMC, b1, nullptr, nullptr);
  // 7) out = x2 + alpha * (h @ w2 + b2)  (fp32 out)
  gemm_bf16<M_BIAS_RES><<<dim3(DIMC/128, NROWS/128), 256, 0, stream>>>(
      hbuf, wT_2, out, NROWS, DIMC, HIDC, b2, x2, alphap);
}

// Round 8
// 985.988 us; speedup vs baseline: 1.1765x; 1.1765x over previous
//
#include <hip/hip_runtime.h>
#include <hip/hip_bf16.h>
#include <math.h>

#define DIMC 1024
#define NHEADC 16
#define DKC 64
#define HIDC 8192
#define TSEQ 2048
#define BATCH 2
#define NROWS (BATCH*TSEQ)   // 4096
#define EPSF 1e-5f

typedef __attribute__((ext_vector_type(8))) short short8;
typedef __attribute__((ext_vector_type(4))) float floatx4;

// ---------------- helpers ----------------
__device__ __forceinline__ unsigned pk2bf(float a, float b){
  float2 t; t.x = a; t.y = b;
  __hip_bfloat162 h = __float22bfloat162_rn(t);   // v_cvt_pk_bf16_f32 on gfx950
  union { __hip_bfloat162 h; unsigned u; } cv; cv.h = h;
  return cv.u;                                    // a in low 16, b in high 16
}
__device__ __forceinline__ ushort f2bf(float f){
  return (ushort)(pk2bf(f, f) & 0xFFFFu);
}
__device__ __forceinline__ floatx4 mfma16(short8 a, short8 b, floatx4 c){
  return __builtin_amdgcn_mfma_f32_16x16x32_bf16(a, b, c, 0, 0, 0);
}
__device__ __forceinline__ void gld_lds16(const void* g, void* l){
  __builtin_amdgcn_global_load_lds((const __attribute__((address_space(1))) unsigned*)g,
                                   (__attribute__((address_space(3))) unsigned*)l, 16, 0, 0);
}
__device__ __forceinline__ float wred_add(float v){
  #pragma unroll
  for (int o = 32; o > 0; o >>= 1) v += __shfl_xor(v, o, 64);
  return v;
}
__device__ __forceinline__ int wred_addi(int v){
  #pragma unroll
  for (int o = 32; o > 0; o >>= 1) v += __shfl_xor(v, o, 64);
  return v;
}
__device__ __forceinline__ unsigned wred_maxu(unsigned v){
  #pragma unroll
  for (int o = 32; o > 0; o >>= 1) { unsigned w = __shfl_xor((int)v, o, 64); v = v > w ? v : w; }
  return v;
}
__device__ __forceinline__ unsigned wred_minu(unsigned v){
  #pragma unroll
  for (int o = 32; o > 0; o >>= 1) { unsigned w = __shfl_xor((int)v, o, 64); v = v < w ? v : w; }
  return v;
}
__device__ __forceinline__ float lo16f(unsigned u){ return __uint_as_float(u << 16); }
__device__ __forceinline__ float hi16f(unsigned u){ return __uint_as_float(u & 0xFFFF0000u); }
// packed bf16-bits -> packed monotone u16 keys (per half: sign? ~b : b|0x8000)
__device__ __forceinline__ unsigned pk2key(unsigned u){
  const unsigned s = u & 0x80008000u;
  return u ^ (0x80008000u | (s - (s >> 15)));
}
// inverse: packed keys -> original packed bf16 bits
__device__ __forceinline__ unsigned key2pk(unsigned k){
  const unsigned s = k & 0x80008000u;
  return k ^ ~(s - (s >> 15));
}

// ---------------- weight transpose + fp32->bf16 convert: W[K][N] -> WT[N][K] ----
__global__ __launch_bounds__(256)
void wconv_t(const float* __restrict__ W, ushort* __restrict__ WT, int K, int N)
{
  __shared__ float tile[32][33];
  const int t = threadIdx.x, tx = t & 31, ty = t >> 5;
  const int n0 = blockIdx.x * 32, k0 = blockIdx.y * 32;
  #pragma unroll
  for (int r = 0; r < 4; ++r)
    tile[ty + r*8][tx] = W[(size_t)(k0 + ty + r*8) * N + n0 + tx];
  __syncthreads();
  #pragma unroll
  for (int r = 0; r < 4; ++r)
    WT[(size_t)(n0 + ty + r*8) * K + k0 + tx] = f2bf(tile[tx][ty + r*8]);
}

// ---------------- V transpose: qkv V-part -> vT[bh][64][2048] ----------------
__global__ __launch_bounds__(256)
void vtrans(const ushort* __restrict__ qkv, ushort* __restrict__ vT)
{
  const int d = threadIdx.x & 63, tp = threadIdx.x >> 6;
  const int bh = blockIdx.y; const int h = bh & 15, b = bh >> 4;
  const int t0 = blockIdx.x * 32 + tp * 8;
  const ushort* src = qkv + ((size_t)(b*TSEQ) + t0) * (3*DIMC) + 2*DIMC + h*DKC + d;
  ushort tmp[8];
  #pragma unroll
  for (int k = 0; k < 8; ++k) tmp[k] = src[(size_t)k * (3*DIMC)];
  *(short8*)&vT[((size_t)bh*DKC + d)*TSEQ + t0] = *(const short8*)tmp;
}

// ---------------- LayerNorm fp32 in -> bf16 out ----------------
__global__ __launch_bounds__(256)
void ln_bf16(const float* __restrict__ x, const float* __restrict__ g,
             const float* __restrict__ b, ushort* __restrict__ y)
{
  __shared__ float red[8];
  const int row = blockIdx.x;
  const float* xr = x + (size_t)row * DIMC;
  const int c = threadIdx.x * 4;
  float4 v = *(const float4*)&xr[c];
  float s  = v.x + v.y + v.z + v.w;
  float ss = v.x*v.x + v.y*v.y + v.z*v.z + v.w*v.w;
  s = wred_add(s); ss = wred_add(ss);
  const int warp = threadIdx.x >> 6, lane = threadIdx.x & 63;
  if (lane == 0) { red[warp] = s; red[4+warp] = ss; }
  __syncthreads();
  s  = red[0] + red[1] + red[2] + red[3];
  ss = red[4] + red[5] + red[6] + red[7];
  const float mu  = s  * (1.f/DIMC);
  const float var = ss * (1.f/DIMC) - mu*mu;
  const float rr  = rsqrtf(var + EPSF);
  const float4 gv = *(const float4*)&g[c];
  const float4 bv = *(const float4*)&b[c];
  uint2 o;
  o.x = pk2bf((v.x-mu)*rr*gv.x + bv.x, (v.y-mu)*rr*gv.y + bv.y);
  o.y = pk2bf((v.z-mu)*rr*gv.z + bv.z, (v.w-mu)*rr*gv.w + bv.w);
  *(uint2*)&y[(size_t)row*DIMC + c] = o;
}

// ---------------- bf16 MFMA GEMM: C[M,N] = A[M,K] @ BT[N,K]^T (+ epilogue) ----
#define M_PLAIN 0      // out bf16
#define M_RES 1        // out fp32: C = res + alpha*acc
#define M_BIAS_GELU 2  // out bf16: C = gelu_exact(acc + bias)
#define M_BIAS_RES 3   // out fp32: C = res + alpha*(acc + bias)

template<int MODE>
__global__ __launch_bounds__(256)
void gemm_bf16(const ushort* __restrict__ A, const ushort* __restrict__ BT,
               void* __restrict__ Cout, const int M, const int N, const int K,
               const float* __restrict__ bias, const float* __restrict__ res,
               const float* __restrict__ alphap)
{
  __shared__ __align__(16) ushort Al[4][128][8];
  __shared__ __align__(16) ushort Bl[4][128][8];
  const int t = threadIdx.x;
  const int lane = t & 63, warp = t >> 6;
  const int quad = lane >> 4, l16 = lane & 15;
  const int m0 = (warp & 1) * 64, n0 = (warp >> 1) * 64;
  const size_t row0 = (size_t)blockIdx.y * 128;
  const size_t col0 = (size_t)blockIdx.x * 128;

  const int c0 = t, c1 = t + 256;
  const int ar0 = c0 & 127, as0 = c0 >> 7;
  const int ar1 = c1 & 127, as1 = c1 >> 7;
  const ushort* pa0 = A  + (row0 + ar0) * (size_t)K + as0 * 8;
  const ushort* pa1 = A  + (row0 + ar1) * (size_t)K + as1 * 8;
  const ushort* pb0 = BT + (col0 + ar0) * (size_t)K + as0 * 8;
  const ushort* pb1 = BT + (col0 + ar1) * (size_t)K + as1 * 8;
  ushort* la0 = &Al[as0][ar0][0];
  ushort* la1 = &Al[as1][ar1][0];
  ushort* lb0 = &Bl[as0][ar0][0];
  ushort* lb1 = &Bl[as1][ar1][0];

  floatx4 acc[4][4];
  const floatx4 zf = {0.f, 0.f, 0.f, 0.f};
  #pragma unroll
  for (int i = 0; i < 4; ++i)
    #pragma unroll
    for (int j = 0; j < 4; ++j) acc[i][j] = zf;

  for (int k0 = 0; k0 < K; k0 += 32) {
    gld_lds16(pa0 + k0, la0);
    gld_lds16(pa1 + k0, la1);
    gld_lds16(pb0 + k0, lb0);
    gld_lds16(pb1 + k0, lb1);
    __syncthreads();
    short8 af[4], bfr[4];
    #pragma unroll
    for (int i = 0; i < 4; ++i) {
      af[i]  = *(const short8*)&Al[quad][m0 + i*16 + l16][0];
      bfr[i] = *(const short8*)&Bl[quad][n0 + i*16 + l16][0];
    }
    #pragma unroll
    for (int mt = 0; mt < 4; ++mt)
      #pragma unroll
      for (int nt = 0; nt < 4; ++nt)
        acc[mt][nt] = mfma16(af[mt], bfr[nt], acc[mt][nt]);
    __syncthreads();
  }

  float alpha = 0.f;
  if (MODE == M_RES || MODE == M_BIAS_RES) alpha = alphap[0];
  #pragma unroll
  for (int nt = 0; nt < 4; ++nt) {
    const size_t col = col0 + n0 + nt*16 + l16;
    float bv = 0.f;
    if (MODE == M_BIAS_GELU || MODE == M_BIAS_RES) bv = bias[col];
    #pragma unroll
    for (int mt = 0; mt < 4; ++mt) {
      const size_t r0 = row0 + m0 + mt*16 + quad*4;
      #pragma unroll
      for (int reg = 0; reg < 4; ++reg) {
        float v = acc[mt][nt][reg];
        if (MODE == M_BIAS_GELU || MODE == M_BIAS_RES) v += bv;
        if (MODE == M_BIAS_GELU) v = 0.5f*v*(1.f + erff(v*0.70710678118654752f));
        if (MODE == M_RES || MODE == M_BIAS_RES) v = res[(r0+reg)*(size_t)N + col] + alpha*v;
        if (MODE == M_PLAIN || MODE == M_BIAS_GELU)
          ((ushort*)Cout)[(r0+reg)*(size_t)N + col] = f2bf(v);
        else
          ((float*)Cout)[(r0+reg)*(size_t)N + col] = v;
      }
    }
  }
}

// ---------------- fused MFMA attention ----------------
// v8: back to the r5 shape (1024 thr / 16 waves / 16-row strip / 2 blocks/CU
// at 88% occupancy — r7 proved smaller strips double per-row K/V streaming
// cost and lose occupancy). Phase 2 is now LDS-RESIDENT BY CONSTRUCTION:
// scores are converted in-place to monotone u16 keys, and every pass
// (radix rounds, classification, denominators, weight write) re-reads its 8
// uint2 from LDS. No register array exists -> neither the allocator's
// LDS-remat gamble (r1) nor the constant ~7-dw scratch spill at the 32-arch-
// VGPR split (r0/r2-r6, 95-122 MB WRITE) can occur; ~25 live regs fit 32.
// Element ownership j = 4*lane + 256*p keeps uint2 reads aligned and
// bank-conflict-free under the phase-1 swizzle.
__device__ __forceinline__ int swzf(int q){ return ((q>>2) ^ q) & 7; }
__device__ __forceinline__ int sidx(int q, int j){
  return (q << 11) + ((((j >> 3) ^ swzf(q)) << 3) | (j & 7));
}

__global__ __launch_bounds__(1024, 8)
void attn_mfma(const ushort* __restrict__ qkv, const ushort* __restrict__ vT,
               const float* __restrict__ alpha_head, ushort* __restrict__ att)
{
  __shared__ __align__(16) ushort S[16*2048];
  __shared__ float Ored[3][4][16*17];
  const int t = threadIdx.x;
  const int lane = t & 63, warp = t >> 6;
  const int quad = lane >> 4, l16 = lane & 15;
  const int blk = blockIdx.x;            // 4096 = 32 bh * 128 q-chunks
  const int bh  = blk >> 7;
  const int q0  = (blk & 127) << 4;
  const int h = bh & (NHEADC-1), b = bh >> 4;
  const size_t rowbase = (size_t)b * TSEQ;
  const floatx4 zf = {0.f, 0.f, 0.f, 0.f};

  // --- phase 1: raw scores S[q][j] = Q.K^T (scale folded into exp2 constant) ---
  {
    const ushort* Qp = qkv + (rowbase + q0 + l16) * (size_t)(3*DIMC) + h*DKC + quad*8;
    const short8 aq0 = *(const short8*)Qp;
    const short8 aq1 = *(const short8*)(Qp + 32);
    const int j0w = warp * 128;
    #pragma unroll
    for (int jt = 0; jt < 8; ++jt) {
      const int j = j0w + jt*16;
      const ushort* Kp = qkv + (rowbase + j + l16) * (size_t)(3*DIMC) + DIMC + h*DKC + quad*8;
      const short8 kb0 = *(const short8*)Kp;
      const short8 kb1 = *(const short8*)(Kp + 32);
      floatx4 c = mfma16(aq0, kb0, zf);
      c = mfma16(aq1, kb1, c);
      #pragma unroll
      for (int r = 0; r < 4; ++r)
        S[sidx(quad*4 + r, j + l16)] = f2bf(c[r]);
    }
  }
  __syncthreads();

  // --- phase 2: per-row exact top-64 + softmax mix; 1 row per wave; LDS-resident ---
  const float SC2 = 0.125f * 1.4426950408889634f;   // (1/sqrt(dk)) * log2(e)
  const float gate = 1.f / (1.f + __expf(-alpha_head[h]));
  {
    const int q = warp;
    const int sbase = q << 11;
    const int swq = swzf(q);
    // lane owns elements j = 4*lane + 256*p + e  (p in [0,8), e in [0,4)).
    // ushort index of the owned uint2 for stride p: a0 + 256*p (8B aligned,
    // conflict-free: consecutive lane pairs hit consecutive 16B groups).
    const int a0 = sbase + 8*(((lane >> 1) ^ swq)) + 4*(lane & 1);

    // pass 0: bf16 -> monotone u16 keys IN PLACE; lane-local max of 32
    unsigned lmxk = 0u;
    #pragma unroll
    for (int p = 0; p < 8; ++p) {
      uint2 w = *(const uint2*)&S[a0 + 256*p];
      const unsigned k0 = pk2key(w.x), k1 = pk2key(w.y);
      w.x = k0; w.y = k1;
      *(uint2*)&S[a0 + 256*p] = w;
      unsigned m0 = (k0 & 0xFFFFu) > (k0 >> 16) ? (k0 & 0xFFFFu) : (k0 >> 16);
      unsigned m1 = (k1 & 0xFFFFu) > (k1 >> 16) ? (k1 & 0xFFFFu) : (k1 >> 16);
      m0 = m0 > m1 ? m0 : m1;
      lmxk = lmxk > m0 ? lmxk : m0;
    }
    const unsigned kmx = wred_maxu(lmxk);
    const unsigned klb = wred_minu(lmxk);  // 64 lane-maxima => 64th-largest key >= klb
    const unsigned mb = (kmx >= 0x8000u) ? (kmx - 0x8000u) : (0xFFFFu - kmx);
    const float nc = -__uint_as_float(mb << 16) * SC2;

    // radix-select the 64th-largest key in [klb, kmx]; start below common prefix
    const unsigned diff = kmx ^ klb;
    unsigned prefix;
    int hb;
    if (diff == 0u) { prefix = kmx; hb = -1; }
    else {
      hb = 31 - __builtin_clz(diff);             // <=15 (16-bit keys)
      prefix = kmx & ~((2u << hb) - 1u);
    }
    hb = __builtin_amdgcn_readfirstlane(hb);
    for (int bit = hb; bit >= 0; --bit) {
      const int cand = (int)(prefix | (1u << bit));
      int c = 32;                                // flag-free count of (key >= cand)
      #pragma unroll
      for (int p = 0; p < 8; ++p) {
        const uint2 w = *(const uint2*)&S[a0 + 256*p];
        c += ((int)(w.x & 0xFFFFu) - cand) >> 31;   // -1 if key < cand
        c += ((int)(w.x >> 16)     - cand) >> 31;
        c += ((int)(w.y & 0xFFFFu) - cand) >> 31;
        c += ((int)(w.y >> 16)     - cand) >> 31;
      }
      c = wred_addi(c);
      prefix = (c >= 64) ? (unsigned)cand : prefix;
    }

    // classification sweep: strict-greater bits + equal bits (one LDS pass)
    const int pfx = (int)prefix;
    unsigned inmask = 0u, eqmask = 0u;
    int cg = 0;
    #pragma unroll
    for (int p = 0; p < 8; ++p) {
      const uint2 w = *(const uint2*)&S[a0 + 256*p];
      const unsigned k0 = w.x & 0xFFFFu, k1 = w.x >> 16;
      const unsigned k2 = w.y & 0xFFFFu, k3 = w.y >> 16;
      const unsigned g0 = (unsigned)((pfx - (int)k0) >> 31) & 1u;   // k > pfx
      const unsigned g1 = (unsigned)((pfx - (int)k1) >> 31) & 1u;
      const unsigned g2 = (unsigned)((pfx - (int)k2) >> 31) & 1u;
      const unsigned g3 = (unsigned)((pfx - (int)k3) >> 31) & 1u;
      cg += (int)(g0 + g1 + g2 + g3);
      inmask |= (g0 << (4*p)) | (g1 << (4*p+1)) | (g2 << (4*p+2)) | (g3 << (4*p+3));
      eqmask |= ((unsigned)(k0 == prefix) << (4*p))   | ((unsigned)(k1 == prefix) << (4*p+1))
              | ((unsigned)(k2 == prefix) << (4*p+2)) | ((unsigned)(k3 == prefix) << (4*p+3));
    }
    const int c_gt = wred_addi(cg);
    const int need_eq = 64 - c_gt;   // >=1

    // tie ordering by lowest j (jax top_k order) — register masks only
    int eqb = 0;
    const unsigned long long below = (1ULL << lane) - 1ULL;
    #pragma unroll
    for (int p = 0; p < 8; ++p) {
      const bool e0 = (eqmask >> (4*p))   & 1u;
      const bool e1 = (eqmask >> (4*p+1)) & 1u;
      const bool e2 = (eqmask >> (4*p+2)) & 1u;
      const bool e3 = (eqmask >> (4*p+3)) & 1u;
      const unsigned long long m0 = __ballot(e0);
      const unsigned long long m1 = __ballot(e1);
      const unsigned long long m2 = __ballot(e2);
      const unsigned long long m3 = __ballot(e3);
      if (m0 | m1 | m2 | m3) {
        int r = eqb + __popcll(m0 & below) + __popcll(m1 & below)
                    + __popcll(m2 & below) + __popcll(m3 & below);
        if (e0) { if (r < need_eq) inmask |= 1u << (4*p);   ++r; }
        if (e1) { if (r < need_eq) inmask |= 1u << (4*p+1); ++r; }
        if (e2) { if (r < need_eq) inmask |= 1u << (4*p+2); ++r; }
        if (e3) { if (r < need_eq) inmask |= 1u << (4*p+3); ++r; }
        eqb += __popcll(m0) + __popcll(m1) + __popcll(m2) + __popcll(m3);
      }
    }

    // denominators (keys -> bf16 scores -> exp, f32)
    float sum_all = 0.f, sum_sp = 0.f;
    #pragma unroll
    for (int p = 0; p < 8; ++p) {
      const uint2 w = *(const uint2*)&S[a0 + 256*p];
      const unsigned s0 = key2pk(w.x), s1 = key2pk(w.y);
      const float e0 = exp2f(fmaf(lo16f(s0), SC2, nc));
      const float e1 = exp2f(fmaf(hi16f(s0), SC2, nc));
      const float e2 = exp2f(fmaf(lo16f(s1), SC2, nc));
      const float e3 = exp2f(fmaf(hi16f(s1), SC2, nc));
      sum_all += (e0 + e1) + (e2 + e3);
      sum_sp  += ((inmask >> (4*p))   & 1u) ? e0 : 0.f;
      sum_sp  += ((inmask >> (4*p+1)) & 1u) ? e1 : 0.f;
      sum_sp  += ((inmask >> (4*p+2)) & 1u) ? e2 : 0.f;
      sum_sp  += ((inmask >> (4*p+3)) & 1u) ? e3 : 0.f;
    }
    sum_all = wred_add(sum_all);
    sum_sp  = wred_add(sum_sp);

    const float cd  = gate / sum_all;
    const float cdc = cd + (1.f - gate) / sum_sp;
    // weight write (re-read keys, recompute exp, scale, pack to bf16)
    #pragma unroll
    for (int p = 0; p < 8; ++p) {
      uint2 w = *(const uint2*)&S[a0 + 256*p];
      const unsigned s0 = key2pk(w.x), s1 = key2pk(w.y);
      const float e0 = exp2f(fmaf(lo16f(s0), SC2, nc));
      const float e1 = exp2f(fmaf(hi16f(s0), SC2, nc));
      const float e2 = exp2f(fmaf(lo16f(s1), SC2, nc));
      const float e3 = exp2f(fmaf(hi16f(s1), SC2, nc));
      const float w0 = e0 * (((inmask >> (4*p))   & 1u) ? cdc : cd);
      const float w1 = e1 * (((inmask >> (4*p+1)) & 1u) ? cdc : cd);
      const float w2 = e2 * (((inmask >> (4*p+2)) & 1u) ? cdc : cd);
      const float w3 = e3 * (((inmask >> (4*p+3)) & 1u) ? cdc : cd);
      w.x = pk2bf(w0, w1);
      w.y = pk2bf(w2, w3);
      *(uint2*)&S[a0 + 256*p] = w;
    }
  }
  __syncthreads();

  // --- phase 3: O[16q x 64d] = W[16x2048] @ V[2048x64]; 4x4 (n,k) wave grid ---
  const int ng = warp & 3, kq = warp >> 2;
  const int n0  = ng * 16;
  const int kt0 = kq * 16;
  floatx4 o = zf, o2 = zf;
  const ushort* Vb = vT + ((size_t)bh*DKC + n0 + l16) * TSEQ + quad*8;
  #pragma unroll 2
  for (int tt = 0; tt < 16; tt += 2) {
    const int kt = kt0 + tt;
    const short8 a0v = *(const short8*)&S[sidx(l16, kt*32 + quad*8)];
    const short8 vb0 = *(const short8*)(Vb + (size_t)kt*32);
    const short8 a1v = *(const short8*)&S[sidx(l16, (kt+1)*32 + quad*8)];
    const short8 vb1 = *(const short8*)(Vb + (size_t)(kt+1)*32);
    o  = mfma16(a0v, vb0, o);
    o2 = mfma16(a1v, vb1, o2);
  }
  o = o + o2;
  if (kq > 0) {
    #pragma unroll
    for (int r = 0; r < 4; ++r) Ored[kq-1][ng][(quad*4+r)*17 + l16] = o[r];
  }
  __syncthreads();
  if (kq == 0) {
    #pragma unroll
    for (int r = 0; r < 4; ++r) {
      const int ri = (quad*4+r)*17 + l16;
      const float v = o[r] + Ored[0][ng][ri] + Ored[1][ng][ri] + Ored[2][ng][ri];
      att[(rowbase + q0 + quad*4 + r) * (size_t)DIMC + h*DKC + n0 + l16] = f2bf(v);
    }
  }
}

// ---------------- launch ----------------
extern "C" void kernel_launch(void* const* d_in, const int* in_sizes, int n_in,
                              void* d_out, int out_size, void* d_ws, size_t ws_size,
                              hipStream_t stream)
{
  const float* x          = (const float*)d_in[0];
  const float* ln1_g      = (const float*)d_in[1];
  const float* ln1_b      = (const float*)d_in[2];
  const float* w_qkv      = (const float*)d_in[3];
  const float* alpha_head = (const float*)d_in[4];
  const float* w_out      = (const float*)d_in[5];
  const float* ln2_g      = (const float*)d_in[6];
  const float* ln2_b      = (const float*)d_in[7];
  const float* w1         = (const float*)d_in[8];
  const float* b1         = (const float*)d_in[9];
  const float* w2         = (const float*)d_in[10];
  const float* b2         = (const float*)d_in[11];
  const float* alphap     = (const float*)d_in[12];
  float* out = (float*)d_out;

  char* ws = (char*)d_ws;
  ushort* wT_qkv = (ushort*)(ws);                         //  6 MB  [3072][1024]
  ushort* wT_out = (ushort*)(ws + 6291456);               //  2 MB  [1024][1024]
  ushort* wT_1   = (ushort*)(ws + 8388608);               // 16 MB  [8192][1024]
  ushort* wT_2   = (ushort*)(ws + 25165824);              // 16 MB  [1024][8192]
  ushort* xn     = (ushort*)(ws + 41943040);              //  8 MB  [4096][1024]
  ushort* qkv    = (ushort*)(ws + 50331648);              // 24 MB  [4096][3072]
  ushort* attb   = (ushort*)(ws + 75497472);              //  8 MB  [4096][1024]
  float*  x2     = (float*) (ws + 83886080);              // 16 MB  [4096][1024]
  ushort* hbuf   = (ushort*)(ws + 100663296);             // 64 MB  [4096][8192]
  ushort* vT     = (ushort*)(ws + 167772160);             //  8 MB  [32][64][2048]

  wconv_t<<<dim3(3072/32, 1024/32), 256, 0, stream>>>(w_qkv, wT_qkv, 1024, 3072);
  wconv_t<<<dim3(1024/32, 1024/32), 256, 0, stream>>>(w_out, wT_out, 1024, 1024);
  wconv_t<<<dim3(8192/32, 1024/32), 256, 0, stream>>>(w1,    wT_1,   1024, 8192);
  wconv_t<<<dim3(1024/32, 8192/32), 256, 0, stream>>>(w2,    wT_2,   8192, 1024);

  // 1) LN1 -> bf16
  ln_bf16<<<NROWS, 256, 0, stream>>>(x, ln1_g, ln1_b, xn);
  // 2) qkv = xn @ w_qkv  (bf16 out)
  gemm_bf16<M_PLAIN><<<dim3(3*DIMC/128, NROWS/128), 256, 0, stream>>>(
      xn, wT_qkv, qkv, NROWS, 3*DIMC, DIMC, nullptr, nullptr, nullptr);
  // 2b) V transpose
  vtrans<<<dim3(64, 32), 256, 0, stream>>>(qkv, vT);
  // 3) adaptive sparse attention (bf16 out)
  attn_mfma<<<4096, 1024, 0, stream>>>(qkv, vT, alpha_head, attb);
  // 4) x2 = x + alpha * (att @ w_out)  (fp32 out)
  gemm_bf16<M_RES><<<dim3(DIMC/128, NROWS/128), 256, 0, stream>>>(
      attb, wT_out, x2, NROWS, DIMC, DIMC, nullptr, x, alphap);
  // 5) LN2 -> bf16 (reuse xn)
  ln_bf16<<<NROWS, 256, 0, stream>>>(x2, ln2_g, ln2_b, xn);
  // 6) h = gelu(xn @ w1 + b1)  (bf16 out)
  gemm_bf16<M_BIAS_GELU><<<dim3(HIDC/128, NROWS/128), 256, 0, stream>>>(
      xn, wT_1, hbuf, NROWS, HIDC, DIMC, b1, nullptr, nullptr);
  // 7) out = x2 + alpha * (h @ w2 + b2)  (fp32 out)
  gemm_bf16<M_BIAS_RES><<<dim3(DIMC/128, NROWS/128), 256, 0, stream>>>(
      hbuf, wT_2, out, NROWS, DIMC, HIDC, b2, x2, alphap);
}

// Round 9
// 911.250 us; speedup vs baseline: 1.2730x; 1.0820x over previous
//
#include <hip/hip_runtime.h>
#include <hip/hip_bf16.h>
#include <math.h>

#define DIMC 1024
#define NHEADC 16
#define DKC 64
#define HIDC 8192
#define TSEQ 2048
#define BATCH 2
#define NROWS (BATCH*TSEQ)   // 4096
#define EPSF 1e-5f

typedef __attribute__((ext_vector_type(8))) short short8;
typedef __attribute__((ext_vector_type(4))) float floatx4;

// ---------------- helpers ----------------
__device__ __forceinline__ unsigned pk2bf(float a, float b){
  float2 t; t.x = a; t.y = b;
  __hip_bfloat162 h = __float22bfloat162_rn(t);   // v_cvt_pk_bf16_f32 on gfx950
  union { __hip_bfloat162 h; unsigned u; } cv; cv.h = h;
  return cv.u;                                    // a in low 16, b in high 16
}
__device__ __forceinline__ ushort f2bf(float f){
  return (ushort)(pk2bf(f, f) & 0xFFFFu);
}
__device__ __forceinline__ floatx4 mfma16(short8 a, short8 b, floatx4 c){
  return __builtin_amdgcn_mfma_f32_16x16x32_bf16(a, b, c, 0, 0, 0);
}
__device__ __forceinline__ void gld_lds16(const void* g, void* l){
  __builtin_amdgcn_global_load_lds((const __attribute__((address_space(1))) unsigned*)g,
                                   (__attribute__((address_space(3))) unsigned*)l, 16, 0, 0);
}
__device__ __forceinline__ float wred_add(float v){
  #pragma unroll
  for (int o = 32; o > 0; o >>= 1) v += __shfl_xor(v, o, 64);
  return v;
}
__device__ __forceinline__ int wred_addi(int v){
  #pragma unroll
  for (int o = 32; o > 0; o >>= 1) v += __shfl_xor(v, o, 64);
  return v;
}
__device__ __forceinline__ unsigned wred_maxu(unsigned v){
  #pragma unroll
  for (int o = 32; o > 0; o >>= 1) { unsigned w = __shfl_xor((int)v, o, 64); v = v > w ? v : w; }
  return v;
}
__device__ __forceinline__ unsigned wred_minu(unsigned v){
  #pragma unroll
  for (int o = 32; o > 0; o >>= 1) { unsigned w = __shfl_xor((int)v, o, 64); v = v < w ? v : w; }
  return v;
}
__device__ __forceinline__ float lo16f(unsigned u){ return __uint_as_float(u << 16); }
__device__ __forceinline__ float hi16f(unsigned u){ return __uint_as_float(u & 0xFFFF0000u); }
// packed bf16-bits -> packed monotone u16 keys (per half: sign? ~b : b|0x8000)
__device__ __forceinline__ unsigned pk2key(unsigned u){
  const unsigned s = u & 0x80008000u;
  return u ^ (0x80008000u | (s - (s >> 15)));
}
// inverse: packed keys -> original packed bf16 bits
__device__ __forceinline__ unsigned key2pk(unsigned k){
  const unsigned s = k & 0x80008000u;
  return k ^ ~(s - (s >> 15));
}

// ---------------- weight transpose + fp32->bf16 convert: W[K][N] -> WT[N][K] ----
__global__ __launch_bounds__(256)
void wconv_t(const float* __restrict__ W, ushort* __restrict__ WT, int K, int N)
{
  __shared__ float tile[32][33];
  const int t = threadIdx.x, tx = t & 31, ty = t >> 5;
  const int n0 = blockIdx.x * 32, k0 = blockIdx.y * 32;
  #pragma unroll
  for (int r = 0; r < 4; ++r)
    tile[ty + r*8][tx] = W[(size_t)(k0 + ty + r*8) * N + n0 + tx];
  __syncthreads();
  #pragma unroll
  for (int r = 0; r < 4; ++r)
    WT[(size_t)(n0 + ty + r*8) * K + k0 + tx] = f2bf(tile[tx][ty + r*8]);
}

// ---------------- V transpose: qkv V-part -> vT[bh][64][2048] ----------------
__global__ __launch_bounds__(256)
void vtrans(const ushort* __restrict__ qkv, ushort* __restrict__ vT)
{
  const int d = threadIdx.x & 63, tp = threadIdx.x >> 6;
  const int bh = blockIdx.y; const int h = bh & 15, b = bh >> 4;
  const int t0 = blockIdx.x * 32 + tp * 8;
  const ushort* src = qkv + ((size_t)(b*TSEQ) + t0) * (3*DIMC) + 2*DIMC + h*DKC + d;
  ushort tmp[8];
  #pragma unroll
  for (int k = 0; k < 8; ++k) tmp[k] = src[(size_t)k * (3*DIMC)];
  *(short8*)&vT[((size_t)bh*DKC + d)*TSEQ + t0] = *(const short8*)tmp;
}

// ---------------- LayerNorm fp32 in -> bf16 out ----------------
__global__ __launch_bounds__(256)
void ln_bf16(const float* __restrict__ x, const float* __restrict__ g,
             const float* __restrict__ b, ushort* __restrict__ y)
{
  __shared__ float red[8];
  const int row = blockIdx.x;
  const float* xr = x + (size_t)row * DIMC;
  const int c = threadIdx.x * 4;
  float4 v = *(const float4*)&xr[c];
  float s  = v.x + v.y + v.z + v.w;
  float ss = v.x*v.x + v.y*v.y + v.z*v.z + v.w*v.w;
  s = wred_add(s); ss = wred_add(ss);
  const int warp = threadIdx.x >> 6, lane = threadIdx.x & 63;
  if (lane == 0) { red[warp] = s; red[4+warp] = ss; }
  __syncthreads();
  s  = red[0] + red[1] + red[2] + red[3];
  ss = red[4] + red[5] + red[6] + red[7];
  const float mu  = s  * (1.f/DIMC);
  const float var = ss * (1.f/DIMC) - mu*mu;
  const float rr  = rsqrtf(var + EPSF);
  const float4 gv = *(const float4*)&g[c];
  const float4 bv = *(const float4*)&b[c];
  uint2 o;
  o.x = pk2bf((v.x-mu)*rr*gv.x + bv.x, (v.y-mu)*rr*gv.y + bv.y);
  o.y = pk2bf((v.z-mu)*rr*gv.z + bv.z, (v.w-mu)*rr*gv.w + bv.w);
  *(uint2*)&y[(size_t)row*DIMC + c] = o;
}

// ---------------- bf16 MFMA GEMM: C[M,N] = A[M,K] @ BT[N,K]^T (+ epilogue) ----
// ldk = row stride of A/BT in elements (== full K). K = this dispatch's K-loop
// length (== split length when gridDim.z > 1). blockIdx.z selects the K-slice.
#define M_PLAIN 0      // out bf16
#define M_RES 1        // out fp32: C = res + alpha*acc
#define M_BIAS_GELU 2  // out bf16: C = gelu_exact(acc + bias)
#define M_BIAS_RES 3   // out fp32: C = res + alpha*(acc + bias)
#define M_PARTIAL 4    // out fp32 raw acc at Cout + z*M*N (split-K partial)

template<int MODE>
__global__ __launch_bounds__(256)
void gemm_bf16(const ushort* __restrict__ A, const ushort* __restrict__ BT,
               void* __restrict__ Cout, const int M, const int N, const int K,
               const float* __restrict__ bias, const float* __restrict__ res,
               const float* __restrict__ alphap, const int ldk)
{
  __shared__ __align__(16) ushort Al[4][128][8];
  __shared__ __align__(16) ushort Bl[4][128][8];
  const int t = threadIdx.x;
  const int lane = t & 63, warp = t >> 6;
  const int quad = lane >> 4, l16 = lane & 15;
  const int m0 = (warp & 1) * 64, n0 = (warp >> 1) * 64;
  const size_t row0 = (size_t)blockIdx.y * 128;
  const size_t col0 = (size_t)blockIdx.x * 128;
  // split-K slice (z = 0 for non-split dispatches)
  const ushort* Ab = A  + (size_t)blockIdx.z * K;
  const ushort* Bb = BT + (size_t)blockIdx.z * K;

  const int c0 = t, c1 = t + 256;
  const int ar0 = c0 & 127, as0 = c0 >> 7;
  const int ar1 = c1 & 127, as1 = c1 >> 7;
  const ushort* pa0 = Ab + (row0 + ar0) * (size_t)ldk + as0 * 8;
  const ushort* pa1 = Ab + (row0 + ar1) * (size_t)ldk + as1 * 8;
  const ushort* pb0 = Bb + (col0 + ar0) * (size_t)ldk + as0 * 8;
  const ushort* pb1 = Bb + (col0 + ar1) * (size_t)ldk + as1 * 8;
  ushort* la0 = &Al[as0][ar0][0];
  ushort* la1 = &Al[as1][ar1][0];
  ushort* lb0 = &Bl[as0][ar0][0];
  ushort* lb1 = &Bl[as1][ar1][0];

  floatx4 acc[4][4];
  const floatx4 zf = {0.f, 0.f, 0.f, 0.f};
  #pragma unroll
  for (int i = 0; i < 4; ++i)
    #pragma unroll
    for (int j = 0; j < 4; ++j) acc[i][j] = zf;

  for (int k0 = 0; k0 < K; k0 += 32) {
    gld_lds16(pa0 + k0, la0);
    gld_lds16(pa1 + k0, la1);
    gld_lds16(pb0 + k0, lb0);
    gld_lds16(pb1 + k0, lb1);
    __syncthreads();
    short8 af[4], bfr[4];
    #pragma unroll
    for (int i = 0; i < 4; ++i) {
      af[i]  = *(const short8*)&Al[quad][m0 + i*16 + l16][0];
      bfr[i] = *(const short8*)&Bl[quad][n0 + i*16 + l16][0];
    }
    #pragma unroll
    for (int mt = 0; mt < 4; ++mt)
      #pragma unroll
      for (int nt = 0; nt < 4; ++nt)
        acc[mt][nt] = mfma16(af[mt], bfr[nt], acc[mt][nt]);
    __syncthreads();
  }

  float alpha = 0.f;
  if (MODE == M_RES || MODE == M_BIAS_RES) alpha = alphap[0];
  const size_t zoff = (MODE == M_PARTIAL) ? (size_t)blockIdx.z * M * N : 0;
  #pragma unroll
  for (int nt = 0; nt < 4; ++nt) {
    const size_t col = col0 + n0 + nt*16 + l16;
    float bv = 0.f;
    if (MODE == M_BIAS_GELU || MODE == M_BIAS_RES) bv = bias[col];
    #pragma unroll
    for (int mt = 0; mt < 4; ++mt) {
      const size_t r0 = row0 + m0 + mt*16 + quad*4;
      #pragma unroll
      for (int reg = 0; reg < 4; ++reg) {
        float v = acc[mt][nt][reg];
        if (MODE == M_BIAS_GELU || MODE == M_BIAS_RES) v += bv;
        if (MODE == M_BIAS_GELU) v = 0.5f*v*(1.f + erff(v*0.70710678118654752f));
        if (MODE == M_RES || MODE == M_BIAS_RES) v = res[(r0+reg)*(size_t)N + col] + alpha*v;
        if (MODE == M_PLAIN || MODE == M_BIAS_GELU)
          ((ushort*)Cout)[(r0+reg)*(size_t)N + col] = f2bf(v);
        else
          ((float*)Cout)[zoff + (r0+reg)*(size_t)N + col] = v;
      }
    }
  }
}

// ---------------- split-K combine: out = res + alpha*(p0 + p1 [+ bias]) ----
template<bool HB>
__global__ __launch_bounds__(256)
void combine2(const float* __restrict__ p, const float* __restrict__ res,
              const float* __restrict__ bias, const float* __restrict__ alphap,
              float* __restrict__ out)
{
  const int c = threadIdx.x * 4;
  const size_t i = (size_t)blockIdx.x * DIMC + c;
  const float alpha = alphap[0];
  const float4 a = *(const float4*)&p[i];
  const float4 b = *(const float4*)&p[(size_t)NROWS * DIMC + i];
  const float4 r = *(const float4*)&res[i];
  float bx = 0.f, by = 0.f, bz = 0.f, bw = 0.f;
  if (HB) { const float4 bv = *(const float4*)&bias[c]; bx = bv.x; by = bv.y; bz = bv.z; bw = bv.w; }
  float4 o;
  o.x = r.x + alpha * (a.x + b.x + bx);
  o.y = r.y + alpha * (a.y + b.y + by);
  o.z = r.z + alpha * (a.z + b.z + bz);
  o.w = r.w + alpha * (a.w + b.w + bw);
  *(float4*)&out[i] = o;
}

// ---------------- fused MFMA attention ----------------
// v8 structure (UNCHANGED from round 8 — verified): 1024 thr / 16 waves /
// 16-row strip / 2 blocks/CU at ~88% occupancy. Phase 2 is LDS-resident by
// construction (no register array -> no spill at the 32-arch-VGPR split).
__device__ __forceinline__ int swzf(int q){ return ((q>>2) ^ q) & 7; }
__device__ __forceinline__ int sidx(int q, int j){
  return (q << 11) + ((((j >> 3) ^ swzf(q)) << 3) | (j & 7));
}

__global__ __launch_bounds__(1024, 8)
void attn_mfma(const ushort* __restrict__ qkv, const ushort* __restrict__ vT,
               const float* __restrict__ alpha_head, ushort* __restrict__ att)
{
  __shared__ __align__(16) ushort S[16*2048];
  __shared__ float Ored[3][4][16*17];
  const int t = threadIdx.x;
  const int lane = t & 63, warp = t >> 6;
  const int quad = lane >> 4, l16 = lane & 15;
  const int blk = blockIdx.x;            // 4096 = 32 bh * 128 q-chunks
  const int bh  = blk >> 7;
  const int q0  = (blk & 127) << 4;
  const int h = bh & (NHEADC-1), b = bh >> 4;
  const size_t rowbase = (size_t)b * TSEQ;
  const floatx4 zf = {0.f, 0.f, 0.f, 0.f};

  // --- phase 1: raw scores S[q][j] = Q.K^T (scale folded into exp2 constant) ---
  {
    const ushort* Qp = qkv + (rowbase + q0 + l16) * (size_t)(3*DIMC) + h*DKC + quad*8;
    const short8 aq0 = *(const short8*)Qp;
    const short8 aq1 = *(const short8*)(Qp + 32);
    const int j0w = warp * 128;
    #pragma unroll
    for (int jt = 0; jt < 8; ++jt) {
      const int j = j0w + jt*16;
      const ushort* Kp = qkv + (rowbase + j + l16) * (size_t)(3*DIMC) + DIMC + h*DKC + quad*8;
      const short8 kb0 = *(const short8*)Kp;
      const short8 kb1 = *(const short8*)(Kp + 32);
      floatx4 c = mfma16(aq0, kb0, zf);
      c = mfma16(aq1, kb1, c);
      #pragma unroll
      for (int r = 0; r < 4; ++r)
        S[sidx(quad*4 + r, j + l16)] = f2bf(c[r]);
    }
  }
  __syncthreads();

  // --- phase 2: per-row exact top-64 + softmax mix; 1 row per wave; LDS-resident ---
  const float SC2 = 0.125f * 1.4426950408889634f;   // (1/sqrt(dk)) * log2(e)
  const float gate = 1.f / (1.f + __expf(-alpha_head[h]));
  {
    const int q = warp;
    const int sbase = q << 11;
    const int swq = swzf(q);
    // lane owns elements j = 4*lane + 256*p + e  (p in [0,8), e in [0,4)).
    const int a0 = sbase + 8*(((lane >> 1) ^ swq)) + 4*(lane & 1);

    // pass 0: bf16 -> monotone u16 keys IN PLACE; lane-local max of 32
    unsigned lmxk = 0u;
    #pragma unroll
    for (int p = 0; p < 8; ++p) {
      uint2 w = *(const uint2*)&S[a0 + 256*p];
      const unsigned k0 = pk2key(w.x), k1 = pk2key(w.y);
      w.x = k0; w.y = k1;
      *(uint2*)&S[a0 + 256*p] = w;
      unsigned m0 = (k0 & 0xFFFFu) > (k0 >> 16) ? (k0 & 0xFFFFu) : (k0 >> 16);
      unsigned m1 = (k1 & 0xFFFFu) > (k1 >> 16) ? (k1 & 0xFFFFu) : (k1 >> 16);
      m0 = m0 > m1 ? m0 : m1;
      lmxk = lmxk > m0 ? lmxk : m0;
    }
    const unsigned kmx = wred_maxu(lmxk);
    const unsigned klb = wred_minu(lmxk);  // 64 lane-maxima => 64th-largest key >= klb
    const unsigned mb = (kmx >= 0x8000u) ? (kmx - 0x8000u) : (0xFFFFu - kmx);
    const float nc = -__uint_as_float(mb << 16) * SC2;

    // radix-select the 64th-largest key in [klb, kmx]; start below common prefix
    const unsigned diff = kmx ^ klb;
    unsigned prefix;
    int hb;
    if (diff == 0u) { prefix = kmx; hb = -1; }
    else {
      hb = 31 - __builtin_clz(diff);             // <=15 (16-bit keys)
      prefix = kmx & ~((2u << hb) - 1u);
    }
    hb = __builtin_amdgcn_readfirstlane(hb);
    for (int bit = hb; bit >= 0; --bit) {
      const int cand = (int)(prefix | (1u << bit));
      int c = 32;                                // flag-free count of (key >= cand)
      #pragma unroll
      for (int p = 0; p < 8; ++p) {
        const uint2 w = *(const uint2*)&S[a0 + 256*p];
        c += ((int)(w.x & 0xFFFFu) - cand) >> 31;   // -1 if key < cand
        c += ((int)(w.x >> 16)     - cand) >> 31;
        c += ((int)(w.y & 0xFFFFu) - cand) >> 31;
        c += ((int)(w.y >> 16)     - cand) >> 31;
      }
      c = wred_addi(c);
      prefix = (c >= 64) ? (unsigned)cand : prefix;
    }

    // classification sweep: strict-greater bits + equal bits (one LDS pass)
    const int pfx = (int)prefix;
    unsigned inmask = 0u, eqmask = 0u;
    int cg = 0;
    #pragma unroll
    for (int p = 0; p < 8; ++p) {
      const uint2 w = *(const uint2*)&S[a0 + 256*p];
      const unsigned k0 = w.x & 0xFFFFu, k1 = w.x >> 16;
      const unsigned k2 = w.y & 0xFFFFu, k3 = w.y >> 16;
      const unsigned g0 = (unsigned)((pfx - (int)k0) >> 31) & 1u;   // k > pfx
      const unsigned g1 = (unsigned)((pfx - (int)k1) >> 31) & 1u;
      const unsigned g2 = (unsigned)((pfx - (int)k2) >> 31) & 1u;
      const unsigned g3 = (unsigned)((pfx - (int)k3) >> 31) & 1u;
      cg += (int)(g0 + g1 + g2 + g3);
      inmask |= (g0 << (4*p)) | (g1 << (4*p+1)) | (g2 << (4*p+2)) | (g3 << (4*p+3));
      eqmask |= ((unsigned)(k0 == prefix) << (4*p))   | ((unsigned)(k1 == prefix) << (4*p+1))
              | ((unsigned)(k2 == prefix) << (4*p+2)) | ((unsigned)(k3 == prefix) << (4*p+3));
    }
    const int c_gt = wred_addi(cg);
    const int need_eq = 64 - c_gt;   // >=1

    // tie ordering by lowest j (jax top_k order) — register masks only
    int eqb = 0;
    const unsigned long long below = (1ULL << lane) - 1ULL;
    #pragma unroll
    for (int p = 0; p < 8; ++p) {
      const bool e0 = (eqmask >> (4*p))   & 1u;
      const bool e1 = (eqmask >> (4*p+1)) & 1u;
      const bool e2 = (eqmask >> (4*p+2)) & 1u;
      const bool e3 = (eqmask >> (4*p+3)) & 1u;
      const unsigned long long m0 = __ballot(e0);
      const unsigned long long m1 = __ballot(e1);
      const unsigned long long m2 = __ballot(e2);
      const unsigned long long m3 = __ballot(e3);
      if (m0 | m1 | m2 | m3) {
        int r = eqb + __popcll(m0 & below) + __popcll(m1 & below)
                    + __popcll(m2 & below) + __popcll(m3 & below);
        if (e0) { if (r < need_eq) inmask |= 1u << (4*p);   ++r; }
        if (e1) { if (r < need_eq) inmask |= 1u << (4*p+1); ++r; }
        if (e2) { if (r < need_eq) inmask |= 1u << (4*p+2); ++r; }
        if (e3) { if (r < need_eq) inmask |= 1u << (4*p+3); ++r; }
        eqb += __popcll(m0) + __popcll(m1) + __popcll(m2) + __popcll(m3);
      }
    }

    // denominators (keys -> bf16 scores -> exp, f32)
    float sum_all = 0.f, sum_sp = 0.f;
    #pragma unroll
    for (int p = 0; p < 8; ++p) {
      const uint2 w = *(const uint2*)&S[a0 + 256*p];
      const unsigned s0 = key2pk(w.x), s1 = key2pk(w.y);
      const float e0 = exp2f(fmaf(lo16f(s0), SC2, nc));
      const float e1 = exp2f(fmaf(hi16f(s0), SC2, nc));
      const float e2 = exp2f(fmaf(lo16f(s1), SC2, nc));
      const float e3 = exp2f(fmaf(hi16f(s1), SC2, nc));
      sum_all += (e0 + e1) + (e2 + e3);
      sum_sp  += ((inmask >> (4*p))   & 1u) ? e0 : 0.f;
      sum_sp  += ((inmask >> (4*p+1)) & 1u) ? e1 : 0.f;
      sum_sp  += ((inmask >> (4*p+2)) & 1u) ? e2 : 0.f;
      sum_sp  += ((inmask >> (4*p+3)) & 1u) ? e3 : 0.f;
    }
    sum_all = wred_add(sum_all);
    sum_sp  = wred_add(sum_sp);

    const float cd  = gate / sum_all;
    const float cdc = cd + (1.f - gate) / sum_sp;
    // weight write (re-read keys, recompute exp, scale, pack to bf16)
    #pragma unroll
    for (int p = 0; p < 8; ++p) {
      uint2 w = *(const uint2*)&S[a0 + 256*p];
      const unsigned s0 = key2pk(w.x), s1 = key2pk(w.y);
      const float e0 = exp2f(fmaf(lo16f(s0), SC2, nc));
      const float e1 = exp2f(fmaf(hi16f(s0), SC2, nc));
      const float e2 = exp2f(fmaf(lo16f(s1), SC2, nc));
      const float e3 = exp2f(fmaf(hi16f(s1), SC2, nc));
      const float w0 = e0 * (((inmask >> (4*p))   & 1u) ? cdc : cd);
      const float w1 = e1 * (((inmask >> (4*p+1)) & 1u) ? cdc : cd);
      const float w2 = e2 * (((inmask >> (4*p+2)) & 1u) ? cdc : cd);
      const float w3 = e3 * (((inmask >> (4*p+3)) & 1u) ? cdc : cd);
      w.x = pk2bf(w0, w1);
      w.y = pk2bf(w2, w3);
      *(uint2*)&S[a0 + 256*p] = w;
    }
  }
  __syncthreads();

  // --- phase 3: O[16q x 64d] = W[16x2048] @ V[2048x64]; 4x4 (n,k) wave grid ---
  const int ng = warp & 3, kq = warp >> 2;
  const int n0  = ng * 16;
  const int kt0 = kq * 16;
  floatx4 o = zf, o2 = zf;
  const ushort* Vb = vT + ((size_t)bh*DKC + n0 + l16) * TSEQ + quad*8;
  #pragma unroll 2
  for (int tt = 0; tt < 16; tt += 2) {
    const int kt = kt0 + tt;
    const short8 a0v = *(const short8*)&S[sidx(l16, kt*32 + quad*8)];
    const short8 vb0 = *(const short8*)(Vb + (size_t)kt*32);
    const short8 a1v = *(const short8*)&S[sidx(l16, (kt+1)*32 + quad*8)];
    const short8 vb1 = *(const short8*)(Vb + (size_t)(kt+1)*32);
    o  = mfma16(a0v, vb0, o);
    o2 = mfma16(a1v, vb1, o2);
  }
  o = o + o2;
  if (kq > 0) {
    #pragma unroll
    for (int r = 0; r < 4; ++r) Ored[kq-1][ng][(quad*4+r)*17 + l16] = o[r];
  }
  __syncthreads();
  if (kq == 0) {
    #pragma unroll
    for (int r = 0; r < 4; ++r) {
      const int ri = (quad*4+r)*17 + l16;
      const float v = o[r] + Ored[0][ng][ri] + Ored[1][ng][ri] + Ored[2][ng][ri];
      att[(rowbase + q0 + quad*4 + r) * (size_t)DIMC + h*DKC + n0 + l16] = f2bf(v);
    }
  }
}

// ---------------- launch ----------------
extern "C" void kernel_launch(void* const* d_in, const int* in_sizes, int n_in,
                              void* d_out, int out_size, void* d_ws, size_t ws_size,
                              hipStream_t stream)
{
  const float* x          = (const float*)d_in[0];
  const float* ln1_g      = (const float*)d_in[1];
  const float* ln1_b      = (const float*)d_in[2];
  const float* w_qkv      = (const float*)d_in[3];
  const float* alpha_head = (const float*)d_in[4];
  const float* w_out      = (const float*)d_in[5];
  const float* ln2_g      = (const float*)d_in[6];
  const float* ln2_b      = (const float*)d_in[7];
  const float* w1         = (const float*)d_in[8];
  const float* b1         = (const float*)d_in[9];
  const float* w2         = (const float*)d_in[10];
  const float* b2         = (const float*)d_in[11];
  const float* alphap     = (const float*)d_in[12];
  float* out = (float*)d_out;

  char* ws = (char*)d_ws;
  ushort* wT_qkv = (ushort*)(ws);                         //  6 MB  [3072][1024]
  ushort* wT_out = (ushort*)(ws + 6291456);               //  2 MB  [1024][1024]
  ushort* wT_1   = (ushort*)(ws + 8388608);               // 16 MB  [8192][1024]
  ushort* wT_2   = (ushort*)(ws + 25165824);              // 16 MB  [1024][8192]
  ushort* xn     = (ushort*)(ws + 41943040);              //  8 MB  [4096][1024]
  ushort* qkv    = (ushort*)(ws + 50331648);              // 24 MB  [4096][3072]
  ushort* attb   = (ushort*)(ws + 75497472);              //  8 MB  [4096][1024]
  float*  x2     = (float*) (ws + 83886080);              // 16 MB  [4096][1024]
  ushort* hbuf   = (ushort*)(ws + 100663296);             // 64 MB  [4096][8192]
  ushort* vT     = (ushort*)(ws + 167772160);             //  8 MB  [32][64][2048]
  // split-K partials: 2 x 16 MB f32 in the xn+qkv region (both dead when used:
  // steps 4 and 7 run after qkv's last reader (attn) and xn's last reader
  // (step 2 / step 6 resp.); ln2 rewrites xn only after combine2 consumed p0)
  float*  part   = (float*) (ws + 41943040);              // 32 MB  [2][4096][1024]

  wconv_t<<<dim3(3072/32, 1024/32), 256, 0, stream>>>(w_qkv, wT_qkv, 1024, 3072);
  wconv_t<<<dim3(1024/32, 1024/32), 256, 0, stream>>>(w_out, wT_out, 1024, 1024);
  wconv_t<<<dim3(8192/32, 1024/32), 256, 0, stream>>>(w1,    wT_1,   1024, 8192);
  wconv_t<<<dim3(1024/32, 8192/32), 256, 0, stream>>>(w2,    wT_2,   8192, 1024);

  // 1) LN1 -> bf16
  ln_bf16<<<NROWS, 256, 0, stream>>>(x, ln1_g, ln1_b, xn);
  // 2) qkv = xn @ w_qkv  (bf16 out)
  gemm_bf16<M_PLAIN><<<dim3(3*DIMC/128, NROWS/128), 256, 0, stream>>>(
      xn, wT_qkv, qkv, NROWS, 3*DIMC, DIMC, nullptr, nullptr, nullptr, DIMC);
  // 2b) V transpose
  vtrans<<<dim3(64, 32), 256, 0, stream>>>(qkv, vT);
  // 3) adaptive sparse attention (bf16 out)
  attn_mfma<<<4096, 1024, 0, stream>>>(qkv, vT, alpha_head, attb);
  // 4) x2 = x + alpha * (att @ w_out)  — split-K=2 partials + combine
  gemm_bf16<M_PARTIAL><<<dim3(DIMC/128, NROWS/128, 2), 256, 0, stream>>>(
      attb, wT_out, part, NROWS, DIMC, DIMC/2, nullptr, nullptr, nullptr, DIMC);
  combine2<false><<<NROWS, 256, 0, stream>>>(part, x, nullptr, alphap, x2);
  // 5) LN2 -> bf16 (reuse xn — safe: combine2 already consumed part's first 8MB)
  ln_bf16<<<NROWS, 256, 0, stream>>>(x2, ln2_g, ln2_b, xn);
  // 6) h = gelu(xn @ w1 + b1)  (bf16 out)
  gemm_bf16<M_BIAS_GELU><<<dim3(HIDC/128, NROWS/128), 256, 0, stream>>>(
      xn, wT_1, hbuf, NROWS, HIDC, DIMC, b1, nullptr, nullptr, DIMC);
  // 7) out = x2 + alpha * (h @ w2 + b2)  — split-K=2 partials + combine
  gemm_bf16<M_PARTIAL><<<dim3(DIMC/128, NROWS/128, 2), 256, 0, stream>>>(
      hbuf, wT_2, part, NROWS, DIMC, HIDC/2, nullptr, nullptr, nullptr, HIDC);
  combine2<true><<<NROWS, 256, 0, stream>>>(part, x2, b2, alphap, out);
}